// Round 12
// baseline (93.473 us; speedup 1.0000x reference)
//
#include <hip/hip_runtime.h>
#include <math.h>

#define BLOCK 256
#define NPB 128        // samples per block
#define NPAIRS (NPB/2) // 64 packed sample pairs
#define NG (NPAIRS/2)  // 32 groups of 2 pairs

#if __has_builtin(__builtin_amdgcn_exp2f)
#define EXP2F(x) __builtin_amdgcn_exp2f(x)
#else
#define EXP2F(x) exp2f(x)
#endif

typedef float v2f __attribute__((ext_vector_type(2)));
typedef float v4f __attribute__((ext_vector_type(4)));

// out[b,m] = coefN * sum_n exp2(a_n*px + b_n*py - c_n - q_m)
//   a = 2t*sx, b = 2t*sy, c = t*|s|^2, q_m = t*|p_m|^2  (arg always <= 0)
//
// R11 measured ~25.3 cyc/exp vs the 20.8 serialized-issue floor: residual
// ~20% is lgkm exposure (ds_reads consumed in the same unroll group they
// are issued in). Fix under the hard VGPR<=64 constraint (8-wave tier,
// m69 + R10's spill cliff): fully-unrolled software pipeline with prefetch
// distance 1 group (2 j-pairs, 12 regs in flight) -- full unroll makes the
// buffer rotation pure register renaming, no movs (R7's dbuf mistake).
// ds count per group cut 4->3 by packing both pairs' c as one v4f.
__global__ __launch_bounds__(BLOCK) void kde_kernel(
    const float* __restrict__ inputs,   // (B, N, 2)
    const float* __restrict__ points,   // (M, 2)
    float* __restrict__ out,            // (B, M), pre-zeroed
    int N, int M, float t, float t2, float coefN)
{
    const int b   = blockIdx.y;
    const int n0  = blockIdx.x * NPB;
    const int tid = (int)threadIdx.x;

    __shared__ v4f SAB[NPAIRS];         // {a0,a1,b0,b1} per sample pair (1 KB)
    __shared__ v4f SC2[NG];             // {c0,c1,c2,c3} per group (512 B)

    if (tid < NPAIRS) {
        // two consecutive samples: (sx0, sy0, sx1, sy1)
        const float4 s2 =
            reinterpret_cast<const float4*>(inputs)[((b * N + n0) >> 1) + tid];
        SAB[tid] = (v4f){t2 * s2.x, t2 * s2.z, t2 * s2.y, t2 * s2.w};
    }
    if (tid < NG) {
        const float4 sa =
            reinterpret_cast<const float4*>(inputs)[((b * N + n0) >> 1) + 2 * tid];
        const float4 sb =
            reinterpret_cast<const float4*>(inputs)[((b * N + n0) >> 1) + 2 * tid + 1];
        SC2[tid] = (v4f){t * fmaf(sa.x, sa.x, sa.y * sa.y),
                         t * fmaf(sa.z, sa.z, sa.w * sa.w),
                         t * fmaf(sb.x, sb.x, sb.y * sb.y),
                         t * fmaf(sb.z, sb.z, sb.w * sb.w)};
    }

    const int m0 = tid;
    const int m1 = tid + BLOCK;
    const float2* pts = reinterpret_cast<const float2*>(points);
    const float2 p0 = pts[m0 < M ? m0 : 0];
    const float2 p1 = pts[m1 < M ? m1 : 0];
    const float q0 = t * fmaf(p0.x, p0.x, p0.y * p0.y);
    const float q1 = t * fmaf(p1.x, p1.x, p1.y * p1.y);

    const v2f PX0 = {p0.x, p0.x}, PY0 = {p0.y, p0.y}, NQ0 = {-q0, -q0};
    const v2f PX1 = {p1.x, p1.x}, PY1 = {p1.y, p1.y}, NQ1 = {-q1, -q1};

    __syncthreads();

    v2f acc0 = {0.f, 0.f}, acc1 = {0.f, 0.f};

    // --- software pipeline, prefetch distance = 1 group ---
    v4f ab0 = SAB[0];
    v4f ab1 = SAB[1];
    v4f c4  = SC2[0];

#pragma unroll
    for (int g = 0; g < NG; ++g) {
        // Prefetch next group (wrap to 0 on last iter: harmless re-read,
        // keeps the loads unconditional and in-bounds).
        const int gn = (g + 1 < NG) ? g + 1 : 0;
        const v4f nab0 = SAB[2 * gn];
        const v4f nab1 = SAB[2 * gn + 1];
        const v4f nc4  = SC2[gn];

        // pair 0 of group
        {
            const v2f a  = {ab0.x, ab0.y};
            const v2f bb = {ab0.z, ab0.w};
            const v2f c  = {c4.x, c4.y};
            const v2f w0 = __builtin_elementwise_fma(a, PX0,
                               __builtin_elementwise_fma(bb, PY0, NQ0 - c));
            const v2f w1 = __builtin_elementwise_fma(a, PX1,
                               __builtin_elementwise_fma(bb, PY1, NQ1 - c));
            v2f e0, e1;
            e0.x = EXP2F(w0.x); e0.y = EXP2F(w0.y);
            e1.x = EXP2F(w1.x); e1.y = EXP2F(w1.y);
            acc0 += e0;
            acc1 += e1;
        }
        // pair 1 of group
        {
            const v2f a  = {ab1.x, ab1.y};
            const v2f bb = {ab1.z, ab1.w};
            const v2f c  = {c4.z, c4.w};
            const v2f w0 = __builtin_elementwise_fma(a, PX0,
                               __builtin_elementwise_fma(bb, PY0, NQ0 - c));
            const v2f w1 = __builtin_elementwise_fma(a, PX1,
                               __builtin_elementwise_fma(bb, PY1, NQ1 - c));
            v2f e0, e1;
            e0.x = EXP2F(w0.x); e0.y = EXP2F(w0.y);
            e1.x = EXP2F(w1.x); e1.y = EXP2F(w1.y);
            acc0 += e0;
            acc1 += e1;
        }

        // rotate (full unroll -> pure renaming, no v_mov)
        ab0 = nab0;
        ab1 = nab1;
        c4  = nc4;
    }

    if (m0 < M) atomicAdd(&out[(size_t)b * M + m0], (acc0.x + acc0.y) * coefN);
    if (m1 < M) atomicAdd(&out[(size_t)b * M + m1], (acc1.x + acc1.y) * coefN);
}

extern "C" void kernel_launch(void* const* d_in, const int* in_sizes, int n_in,
                              void* d_out, int out_size, void* d_ws, size_t ws_size,
                              hipStream_t stream) {
    const float* inputs = (const float*)d_in[0];   // (B, N, 2) fp32
    const float* points = (const float*)d_in[1];   // (M, 2) fp32
    float* out = (float*)d_out;                    // (B, M) fp32

    const int M = in_sizes[1] / 2;          // 512
    const int B = out_size / M;             // 128
    const int N = in_sizes[0] / (2 * B);    // 2048

    // Silverman bandwidth, d = 2
    const double h    = pow(4.0 / 4.0, 1.0 / 6.0) * pow((double)N, -1.0 / 6.0);
    const double h2   = h * h;
    const double coef = 1.0 / (2.0 * M_PI * h2);
    const double td   = 0.5 / (h2 * M_LN2);       // exp(-0.5*sq/h^2) = exp2(-t*sq)
    const float  t     = (float)td;
    const float  t2    = (float)(2.0 * td);
    const float  coefN = (float)(coef / (double)N);

    hipMemsetAsync(out, 0, (size_t)out_size * sizeof(float), stream);

    dim3 grid(N / NPB, B);                  // (16, 128) = 2048 blocks
    kde_kernel<<<grid, BLOCK, 0, stream>>>(inputs, points, out,
                                           N, M, t, t2, coefN);
}

// Round 13
// 72.812 us; speedup vs baseline: 1.2838x; 1.2838x over previous
//
#include <hip/hip_runtime.h>
#include <math.h>

#define BLOCK 256
#define NPB 128        // samples per block
#define NPAIRS (NPB/2) // 64 packed sample pairs

#if __has_builtin(__builtin_amdgcn_exp2f)
#define EXP2F(x) __builtin_amdgcn_exp2f(x)
#else
#define EXP2F(x) exp2f(x)
#endif

typedef float v2f __attribute__((ext_vector_type(2)));
typedef float v4f __attribute__((ext_vector_type(4)));

// out[b,m] = coefN * sum_n exp2(a_n*px + b_n*py - c_n - q_m)
//   a = 2t*sx, b = 2t*sy, c = t*|s|^2, q_m = t*|p_m|^2  (arg always <= 0)
//
// Register-allocation history (keep rolled loops!):
//   R10: __launch_bounds__(256,8) cap 64 + unroll -> 32-reg tier + scratch
//        spills (574 MB traffic, 358 us).
//   R12: FULL unroll of a 32-stage pipeline -> 252 VGPRs, 2 waves/SIMD, 43 us.
//   R11 (base): rolled loop, unroll 4, no min-waves bound -> 22.6 us.
// This round: unroll 8 -- 16 ds_reads batched per group with 32 exps
// (~512 cyc) of cover, in-flight ~80 VGPRs -> ~6 waves/SIMD. Per-exp issue
// model: 16 (exp) + ~4 (pk share) + ~1 (ds share) = 21 cyc; R11 measured
// 25.3 -> stalls at group heads are the target.
__global__ __launch_bounds__(BLOCK) void kde_kernel(
    const float* __restrict__ inputs,   // (B, N, 2)
    const float* __restrict__ points,   // (M, 2)
    float* __restrict__ out,            // (B, M), pre-zeroed
    int N, int M, float t, float t2, float coefN)
{
    const int b   = blockIdx.y;
    const int n0  = blockIdx.x * NPB;
    const int tid = (int)threadIdx.x;

    __shared__ v4f SAB[NPAIRS];         // {a0,a1,b0,b1} per sample pair (1 KB)
    __shared__ v2f SC[NPAIRS];          // {c0,c1} (512 B)

    if (tid < NPAIRS) {
        // two consecutive samples: (sx0, sy0, sx1, sy1)
        const float4 s2 =
            reinterpret_cast<const float4*>(inputs)[((b * N + n0) >> 1) + tid];
        SAB[tid] = (v4f){t2 * s2.x, t2 * s2.z, t2 * s2.y, t2 * s2.w};
        SC[tid]  = (v2f){t * fmaf(s2.x, s2.x, s2.y * s2.y),
                         t * fmaf(s2.z, s2.z, s2.w * s2.w)};
    }

    const int m0 = tid;
    const int m1 = tid + BLOCK;
    const float2* pts = reinterpret_cast<const float2*>(points);
    const float2 p0 = pts[m0 < M ? m0 : 0];
    const float2 p1 = pts[m1 < M ? m1 : 0];
    const float q0 = t * fmaf(p0.x, p0.x, p0.y * p0.y);
    const float q1 = t * fmaf(p1.x, p1.x, p1.y * p1.y);

    const v2f PX0 = {p0.x, p0.x}, PY0 = {p0.y, p0.y}, NQ0 = {-q0, -q0};
    const v2f PX1 = {p1.x, p1.x}, PY1 = {p1.y, p1.y}, NQ1 = {-q1, -q1};

    __syncthreads();

    v2f acc0 = {0.f, 0.f}, acc1 = {0.f, 0.f};

#pragma unroll 8
    for (int j = 0; j < NPAIRS; ++j) {
        const v4f ab = SAB[j];          // ds_read_b128 (broadcast)
        const v2f c  = SC[j];           // ds_read_b64
        const v2f a  = {ab.x, ab.y};
        const v2f bb = {ab.z, ab.w};
        const v2f k0 = NQ0 - c;         // v_pk_add (neg modifier)
        const v2f k1 = NQ1 - c;
        const v2f w0 = __builtin_elementwise_fma(a, PX0,
                           __builtin_elementwise_fma(bb, PY0, k0));
        const v2f w1 = __builtin_elementwise_fma(a, PX1,
                           __builtin_elementwise_fma(bb, PY1, k1));
        v2f e0, e1;
        e0.x = EXP2F(w0.x); e0.y = EXP2F(w0.y);
        e1.x = EXP2F(w1.x); e1.y = EXP2F(w1.y);
        acc0 += e0;                     // v_pk_add_f32
        acc1 += e1;
    }

    if (m0 < M) atomicAdd(&out[(size_t)b * M + m0], (acc0.x + acc0.y) * coefN);
    if (m1 < M) atomicAdd(&out[(size_t)b * M + m1], (acc1.x + acc1.y) * coefN);
}

extern "C" void kernel_launch(void* const* d_in, const int* in_sizes, int n_in,
                              void* d_out, int out_size, void* d_ws, size_t ws_size,
                              hipStream_t stream) {
    const float* inputs = (const float*)d_in[0];   // (B, N, 2) fp32
    const float* points = (const float*)d_in[1];   // (M, 2) fp32
    float* out = (float*)d_out;                    // (B, M) fp32

    const int M = in_sizes[1] / 2;          // 512
    const int B = out_size / M;             // 128
    const int N = in_sizes[0] / (2 * B);    // 2048

    // Silverman bandwidth, d = 2
    const double h    = pow(4.0 / 4.0, 1.0 / 6.0) * pow((double)N, -1.0 / 6.0);
    const double h2   = h * h;
    const double coef = 1.0 / (2.0 * M_PI * h2);
    const double td   = 0.5 / (h2 * M_LN2);       // exp(-0.5*sq/h^2) = exp2(-t*sq)
    const float  t     = (float)td;
    const float  t2    = (float)(2.0 * td);
    const float  coefN = (float)(coef / (double)N);

    hipMemsetAsync(out, 0, (size_t)out_size * sizeof(float), stream);

    dim3 grid(N / NPB, B);                  // (16, 128) = 2048 blocks
    kde_kernel<<<grid, BLOCK, 0, stream>>>(inputs, points, out,
                                           N, M, t, t2, coefN);
}